// Round 1
// baseline (621.573 us; speedup 1.0000x reference)
//
#include <hip/hip_runtime.h>
#include <hip/hip_bf16.h>
#include <stdint.h>

// ---------- types & helpers ----------
typedef __attribute__((ext_vector_type(4))) float f32x4;
typedef __attribute__((ext_vector_type(8))) short s16x8;      // MFMA bf16 frag (8 bf16)
typedef __attribute__((ext_vector_type(8))) unsigned short u16x8;
typedef __attribute__((ext_vector_type(4))) unsigned short u16x4;

static __device__ __forceinline__ float b2f(unsigned short u) {
  union { unsigned int i; float f; } v; v.i = ((unsigned int)u) << 16; return v.f;
}
static __device__ __forceinline__ unsigned short f2b(float f) {
  unsigned int x = __float_as_uint(f);
  return (unsigned short)((x + 0x7fffu + ((x >> 16) & 1u)) >> 16);  // RNE
}

typedef __attribute__((address_space(1))) const void gconst_t;
typedef __attribute__((address_space(3))) void lds_t;
static __device__ __forceinline__ void gload_lds16(const void* g, void* l) {
  __builtin_amdgcn_global_load_lds((gconst_t*)g, (lds_t*)l, 16, 0, 0);
}

// ---------- GEMM template: C[m,n] = sum_k A[m,k]*B[n,k]  (both row-major, bf16) ----------
// m97 structure: 128x128 tile, BK=32, 4 waves (2x2 quadrants of 64x64), 16x16x32 MFMA.
// EPI: 0=plain bf16  1=fp32  2=silu bf16  3=qu/qv/kk split  4=wv (*rinv*gate) bf16
struct GemmP {
  const unsigned short* A; const unsigned short* B; void* C;
  long sA, sB, sC;                 // batch strides (elements)
  int M, N, K, lda, ldb, ldc;
  int causal, kend_mode;
  const float* uvec; const float* vvec;
  unsigned short* qv_out; unsigned short* kk_out; float invtau;
  const float* rinv; const unsigned short* gate;
};

template<int EPI>
__launch_bounds__(256)
__global__ void gemm_bt_k(GemmP p) {
  const int i0 = blockIdx.x * 128;
  const int j0 = blockIdx.y * 128;
  const int b  = blockIdx.z;
  if (p.causal && j0 > i0) return;
  const unsigned short* A = p.A + (long)b * p.sA + (long)i0 * p.lda;
  const unsigned short* B = p.B + (long)b * p.sB + (long)j0 * p.ldb;
  const int kend = p.kend_mode ? min(p.K, i0 + 128) : p.K;

  __shared__ unsigned short As[128 * 32];
  __shared__ unsigned short Bs[128 * 32];

  const int tid = threadIdx.x;
  const int w = tid >> 6, l = tid & 63;
  const int wr = w >> 1, wc = w & 1;

  f32x4 acc[4][4];
#pragma unroll
  for (int m = 0; m < 4; ++m)
#pragma unroll
    for (int n = 0; n < 4; ++n) acc[m][n] = (f32x4){0.f, 0.f, 0.f, 0.f};

  // staging: wave w does passes w and w+4 (16 rows each); lane -> (row l/4, k8 l%4)
  const int srow = (l >> 2);
  const int scol = (l & 3) * 8;
  const unsigned short* ga0 = A + (long)(w * 16 + srow) * p.lda + scol;
  const unsigned short* ga1 = A + (long)((w + 4) * 16 + srow) * p.lda + scol;
  const unsigned short* gb0 = B + (long)(w * 16 + srow) * p.ldb + scol;
  const unsigned short* gb1 = B + (long)((w + 4) * 16 + srow) * p.ldb + scol;
  unsigned short* la0 = As + w * 512;
  unsigned short* la1 = As + (w + 4) * 512;
  unsigned short* lb0 = Bs + w * 512;
  unsigned short* lb1 = Bs + (w + 4) * 512;

  const unsigned short* ap = As + ((wr * 64) + (l & 15)) * 32 + (l >> 4) * 8;
  const unsigned short* bp = Bs + ((wc * 64) + (l & 15)) * 32 + (l >> 4) * 8;

  for (int k0 = 0; k0 < kend; k0 += 32) {
    gload_lds16(ga0 + k0, la0);
    gload_lds16(ga1 + k0, la1);
    gload_lds16(gb0 + k0, lb0);
    gload_lds16(gb1 + k0, lb1);
    __syncthreads();                       // drains vmcnt before barrier
    s16x8 af[4], bfr[4];
#pragma unroll
    for (int m = 0; m < 4; ++m) af[m] = *(const s16x8*)(ap + m * 16 * 32);
#pragma unroll
    for (int n = 0; n < 4; ++n) bfr[n] = *(const s16x8*)(bp + n * 16 * 32);
#pragma unroll
    for (int m = 0; m < 4; ++m)
#pragma unroll
      for (int n = 0; n < 4; ++n)
        acc[m][n] = __builtin_amdgcn_mfma_f32_16x16x32_bf16(af[m], bfr[n], acc[m][n], 0, 0, 0);
    __syncthreads();
  }

  // epilogue: C/D layout col = lane&15, row = (lane>>4)*4 + e  [m89-verified]
  const int rbase = i0 + wr * 64 + (l >> 4) * 4;
  const int cbase = j0 + wc * 64 + (l & 15);
#pragma unroll
  for (int m = 0; m < 4; ++m) {
#pragma unroll
    for (int n = 0; n < 4; ++n) {
      const int col = cbase + n * 16;
#pragma unroll
      for (int e = 0; e < 4; ++e) {
        const int row = rbase + m * 16 + e;
        const float val = acc[m][n][e];
        const long coff = (long)b * p.sC + (long)row * p.ldc + col;
        if constexpr (EPI == 0) {
          ((unsigned short*)p.C)[coff] = f2b(val);
        } else if constexpr (EPI == 1) {
          ((float*)p.C)[coff] = val;
        } else if constexpr (EPI == 2) {
          ((unsigned short*)p.C)[coff] = f2b(val / (1.f + __expf(-val)));
        } else if constexpr (EPI == 3) {
          if (j0 == 0) {                       // cols 0..127 -> qu/qv
            const float q = val * p.invtau;
            const long o = (long)row * 128 + col;
            ((unsigned short*)p.C)[o] = f2b(q + p.uvec[col]);
            p.qv_out[o] = f2b(q + p.vvec[col]);
          } else {                             // cols 128..255 -> k
            p.kk_out[(long)row * 128 + (col - 128)] = f2b(val);
          }
        } else if constexpr (EPI == 4) {
          const float g = b2f(p.gate[coff]);
          const float r = p.rinv[b * p.M + row];
          ((unsigned short*)p.C)[coff] = f2b(val * r * g);
        }
      }
    }
  }
}

// ---------- RMSNorm: x[row,1024] -> bf16 x_tilde ----------
__launch_bounds__(256)
__global__ void rmsnorm_k(const float* __restrict__ x, const float* __restrict__ g,
                          unsigned short* __restrict__ xt) {
  const long row = blockIdx.x;
  const float* xr = x + row * 1024;
  const int t = threadIdx.x;
  const float4 v = ((const float4*)xr)[t];
  float ss = v.x * v.x + v.y * v.y + v.z * v.z + v.w * v.w;
#pragma unroll
  for (int o = 1; o < 64; o <<= 1) ss += __shfl_xor(ss, o);
  __shared__ float wsum[4];
  if ((t & 63) == 0) wsum[t >> 6] = ss;
  __syncthreads();
  const float tot = wsum[0] + wsum[1] + wsum[2] + wsum[3];
  const float r = 1.0f / sqrtf(tot * (1.0f / 1024.0f) + 1e-6f);
  const float4 gv = ((const float4*)g)[t];
  u16x4 o;
  o.x = f2b(v.x * r * gv.x); o.y = f2b(v.y * r * gv.y);
  o.z = f2b(v.z * r * gv.z); o.w = f2b(v.w * r * gv.w);
  ((u16x4*)(xt + row * 1024))[t] = o;
}

// ---------- sinusoid table (UNFLIPPED: rr[d] = xl_r[T-1-d] = sin_noflip[d] @ W_r) ----------
__launch_bounds__(256)
__global__ void sinemb_k(unsigned short* __restrict__ emb) {
  const int idx = blockIdx.x * 256 + threadIdx.x;
  const int t = idx >> 10, w = idx & 1023;
  const int h = w & 511;
  const float inv = __expf(-(float)h * (9.2103403719761836f / 512.0f)); // LAM^(-2h/1024)
  const float pre = (float)t * inv;
  const float val = (w < 512) ? sinf(pre) : cosf(pre);
  emb[idx] = f2b(val);
}

// ---------- transpose-cast fp32 [R,C] -> bf16 [C,R] ----------
__launch_bounds__(256)
__global__ void transcast_k(const float* __restrict__ in, unsigned short* __restrict__ out,
                            int R, int C) {
  __shared__ float tile[32][33];
  const int c0 = blockIdx.x * 32, r0 = blockIdx.y * 32;
  const int tx = threadIdx.x & 31, ty = threadIdx.x >> 5;
#pragma unroll
  for (int k = 0; k < 4; ++k)
    tile[ty + k * 8][tx] = in[(long)(r0 + ty + k * 8) * C + c0 + tx];
  __syncthreads();
#pragma unroll
  for (int k = 0; k < 4; ++k)
    out[(long)(c0 + ty + k * 8) * R + r0 + tx] = f2b(tile[tx][ty + k * 8]);
}

// ---------- E-combine: E = exp(min(AC + BD2[i,i-j],60)) masked, in-place over AC ----------
__launch_bounds__(256)
__global__ void ecombine_k(unsigned short* __restrict__ AC, const unsigned short* __restrict__ BD2,
                           float* __restrict__ stats, int T) {
  const int i0 = blockIdx.x * 128, j0 = blockIdx.y * 128, b = blockIdx.z;
  if (j0 > i0) return;
  const long base = (long)b * T * T;
  unsigned short* E = AC + base;
  const unsigned short* BD = BD2 + base;
  const int tid = threadIdx.x;
#pragma unroll
  for (int pss = 0; pss < 2; ++pss) {
    const int slot = tid + 256 * pss;
    const int r = slot >> 2, ch = slot & 3;     // 4 threads per row, 32 cols each
    const int i = i0 + r;
    const long rowb = (long)i * T;
    const int jbase = j0 + ch * 32;
    float sum = 0.f;
    u16x8 outv[4];
    const u16x8* acp = (const u16x8*)(E + rowb + jbase);
#pragma unroll
    for (int q = 0; q < 4; ++q) {
      const u16x8 av = acp[q];
#pragma unroll
      for (int c = 0; c < 8; ++c) {
        const int j = jbase + q * 8 + c;
        float e;
        if (j > i) {
          e = 0.f;
        } else {
          float s = b2f(av[c]) + b2f(BD[rowb + (i - j)]);
          s = fminf(s, 60.f);
          e = __expf(s);
          sum += e;
        }
        outv[q][c] = f2b(e);
      }
    }
    u16x8* eop = (u16x8*)(E + rowb + jbase);
#pragma unroll
    for (int q = 0; q < 4; ++q) eop[q] = outv[q];
    sum += __shfl_xor(sum, 1);
    sum += __shfl_xor(sum, 2);
    if (ch == 0) stats[((long)(b * T + i) << 5) + (j0 >> 7)] = sum;
  }
}

// ---------- per-row 1/sum ----------
__global__ void rowinv_k(const float* __restrict__ stats, float* __restrict__ rinv,
                         int T, int BT) {
  const int idx = blockIdx.x * 256 + threadIdx.x;
  if (idx >= BT) return;
  const int i = idx & (T - 1);
  const int nt = (i >> 7) + 1;
  const float* st = stats + ((long)idx << 5);
  float s = 0.f;
  for (int jt = 0; jt < nt; ++jt) s += st[jt];
  rinv[idx] = 1.0f / s;
}

// ---------- host ----------
extern "C" void kernel_launch(void* const* d_in, const int* in_sizes, int n_in,
                              void* d_out, int out_size, void* d_ws, size_t ws_size,
                              hipStream_t stream) {
  const float* x    = (const float*)d_in[0];
  const float* g_ln = (const float*)d_in[1];
  const float* W_q  = (const float*)d_in[2];
  const float* W_k  = (const float*)d_in[3];
  const float* W_v  = (const float*)d_in[4];
  const float* W_g  = (const float*)d_in[5];
  const float* W_r  = (const float*)d_in[6];
  const float* xl_u = (const float*)d_in[7];
  const float* xl_v = (const float*)d_in[8];
  const float* W_o  = (const float*)d_in[9];
  float* out = (float*)d_out;

  const int B = 2, T = 4096, D = 1024, K = 128, V = 2048;
  const int BT = B * T;

  char* ws = (char*)d_ws;
  size_t off = 0;
  auto alloc = [&](size_t bytes) -> void* {
    void* p = ws + off; off += (bytes + 255) & ~(size_t)255; return p;
  };
  unsigned short* XT   = (unsigned short*)alloc((size_t)BT * D * 2);
  unsigned short* WQKT = (unsigned short*)alloc((size_t)256 * D * 2);
  unsigned short* WVT  = (unsigned short*)alloc((size_t)V * D * 2);
  unsigned short* WGT  = (unsigned short*)alloc((size_t)V * D * 2);
  unsigned short* WRT  = (unsigned short*)alloc((size_t)K * D * 2);
  unsigned short* WOT  = (unsigned short*)alloc((size_t)D * V * 2);
  unsigned short* QU   = (unsigned short*)alloc((size_t)BT * K * 2);
  unsigned short* QV   = (unsigned short*)alloc((size_t)BT * K * 2);
  unsigned short* KKb  = (unsigned short*)alloc((size_t)BT * K * 2);
  unsigned short* RR   = (unsigned short*)alloc((size_t)T * K * 2);
  unsigned short* VVT  = (unsigned short*)alloc((size_t)V * BT * 2);
  unsigned short* GATE = (unsigned short*)alloc((size_t)BT * V * 2);
  float* STATS         = (float*)alloc((size_t)BT * 32 * 4);
  float* RINV          = (float*)alloc((size_t)BT * 4);
  unsigned short* AC   = (unsigned short*)alloc((size_t)B * T * T * 2);
  unsigned short* BD2  = (unsigned short*)alloc((size_t)B * T * T * 2);
  unsigned short* EMB  = BD2;  // [T,D] bf16, dead before BD2 is written
  unsigned short* WVG  = BD2;  // [BT,V] bf16, written after BD2 is consumed
  if (off > ws_size) return;   // loud failure (output stays zero)
  (void)in_sizes; (void)n_in; (void)out_size;

  const float invtau = 0.08838834764831845f;  // 1/sqrt(128)

  // weight transposes to bf16 [N,K]
  transcast_k<<<dim3(K / 32, D / 32), 256, 0, stream>>>(W_q, WQKT, D, K);
  transcast_k<<<dim3(K / 32, D / 32), 256, 0, stream>>>(W_k, WQKT + (size_t)K * D, D, K);
  transcast_k<<<dim3(V / 32, D / 32), 256, 0, stream>>>(W_v, WVT, D, V);
  transcast_k<<<dim3(V / 32, D / 32), 256, 0, stream>>>(W_g, WGT, D, V);
  transcast_k<<<dim3(K / 32, D / 32), 256, 0, stream>>>(W_r, WRT, D, K);
  transcast_k<<<dim3(D / 32, V / 32), 256, 0, stream>>>(W_o, WOT, V, D);
  rmsnorm_k<<<BT, 256, 0, stream>>>(x, g_ln, XT);
  sinemb_k<<<(T * D) / 256, 256, 0, stream>>>(EMB);

  { // qu/qv/k fused: A=XT[8192,1024], B=WQKT[256,1024]
    GemmP p{}; p.A = XT; p.B = WQKT; p.C = QU;
    p.M = BT; p.N = 256; p.K = D; p.lda = D; p.ldb = D; p.ldc = K;
    p.uvec = xl_u; p.vvec = xl_v; p.qv_out = QV; p.kk_out = KKb; p.invtau = invtau;
    gemm_bt_k<3><<<dim3(BT / 128, 2, 1), 256, 0, stream>>>(p);
  }
  { // rr = sin_noflip @ W_r : A=EMB[4096,1024], B=WRT[128,1024]
    GemmP p{}; p.A = EMB; p.B = WRT; p.C = RR;
    p.M = T; p.N = K; p.K = D; p.lda = D; p.ldb = D; p.ldc = K;
    gemm_bt_k<0><<<dim3(T / 128, K / 128, 1), 256, 0, stream>>>(p);
  }
  { // v^T: A=WVT[2048,1024], B=XT[8192,1024] -> VVT[2048,8192]
    GemmP p{}; p.A = WVT; p.B = XT; p.C = VVT;
    p.M = V; p.N = BT; p.K = D; p.lda = D; p.ldb = D; p.ldc = BT;
    gemm_bt_k<0><<<dim3(V / 128, BT / 128, 1), 256, 0, stream>>>(p);
  }
  { // gate = silu(x~ @ W_g): A=XT, B=WGT -> GATE[8192,2048]
    GemmP p{}; p.A = XT; p.B = WGT; p.C = GATE;
    p.M = BT; p.N = V; p.K = D; p.lda = D; p.ldb = D; p.ldc = V;
    gemm_bt_k<2><<<dim3(BT / 128, V / 128, 1), 256, 0, stream>>>(p);
  }
  { // AC = qu . k^T (causal tiles), batched
    GemmP p{}; p.A = QU; p.B = KKb; p.C = AC;
    p.sA = (long)T * K; p.sB = (long)T * K; p.sC = (long)T * T;
    p.M = T; p.N = T; p.K = K; p.lda = K; p.ldb = K; p.ldc = T; p.causal = 1;
    gemm_bt_k<0><<<dim3(T / 128, T / 128, B), 256, 0, stream>>>(p);
  }
  { // BD2[b,i,d] = qv . rr^T (causal in (i,d)), batched, shared B
    GemmP p{}; p.A = QV; p.B = RR; p.C = BD2;
    p.sA = (long)T * K; p.sB = 0; p.sC = (long)T * T;
    p.M = T; p.N = T; p.K = K; p.lda = K; p.ldb = K; p.ldc = T; p.causal = 1;
    gemm_bt_k<0><<<dim3(T / 128, T / 128, B), 256, 0, stream>>>(p);
  }
  ecombine_k<<<dim3(T / 128, T / 128, B), 256, 0, stream>>>(AC, BD2, STATS, T);
  rowinv_k<<<BT / 256, 256, 0, stream>>>(STATS, RINV, T, BT);
  { // wv = (E @ v) * rinv * gate : A=E(AC), B=VVT(+b*4096), k bounded per row-tile
    GemmP p{}; p.A = AC; p.B = VVT; p.C = WVG;
    p.sA = (long)T * T; p.sB = T; p.sC = (long)T * V;
    p.M = T; p.N = V; p.K = T; p.lda = T; p.ldb = BT; p.ldc = V;
    p.kend_mode = 1; p.rinv = RINV; p.gate = GATE;
    gemm_bt_k<4><<<dim3(T / 128, V / 128, B), 256, 0, stream>>>(p);
  }
  { // res = wvg @ W_o : A=WVG[8192,2048], B=WOT[1024,2048] -> fp32 out
    GemmP p{}; p.A = WVG; p.B = WOT; p.C = out;
    p.M = BT; p.N = D; p.K = V; p.lda = V; p.ldb = V; p.ldc = D;
    gemm_bt_k<1><<<dim3(BT / 128, D / 128, 1), 256, 0, stream>>>(p);
  }
}

// Round 2
// 526.529 us; speedup vs baseline: 1.1805x; 1.1805x over previous
//
#include <hip/hip_runtime.h>
#include <hip/hip_bf16.h>
#include <stdint.h>

// ---------- types & helpers ----------
typedef __attribute__((ext_vector_type(4))) float f32x4;
typedef __attribute__((ext_vector_type(8))) short s16x8;      // MFMA bf16 frag (8 bf16)
typedef __attribute__((ext_vector_type(8))) unsigned short u16x8;
typedef __attribute__((ext_vector_type(4))) unsigned short u16x4;

static __device__ __forceinline__ float b2f(unsigned short u) {
  union { unsigned int i; float f; } v; v.i = ((unsigned int)u) << 16; return v.f;
}
static __device__ __forceinline__ unsigned short f2b(float f) {
  unsigned int x = __float_as_uint(f);
  return (unsigned short)((x + 0x7fffu + ((x >> 16) & 1u)) >> 16);  // RNE
}

typedef __attribute__((address_space(1))) const void gconst_t;
typedef __attribute__((address_space(3))) void lds_t;
static __device__ __forceinline__ void gload_lds16(const void* g, void* l) {
  __builtin_amdgcn_global_load_lds((gconst_t*)g, (lds_t*)l, 16, 0, 0);
}

template<int N>
static __device__ __forceinline__ void vmwait() {
  asm volatile("s_waitcnt vmcnt(%0)" :: "n"(N) : "memory");
}

struct GemmP {
  const unsigned short* A; const unsigned short* B; void* C;
  long sA, sB, sC;                 // batch strides (elements)
  int M, N, K, lda, ldb, ldc;
  int causal, kend_mode;
  const float* uvec; const float* vvec;
  unsigned short* qv_out; unsigned short* kk_out; float invtau;
  const float* rinv; const unsigned short* gate;
};

// ---------- 8-phase-style 256-wide GEMM: C[m,n] = sum_k A[m,k]*B[n,k] ----------
// BM = MREP*32 (128 or 256), BN = 256, BK = 32. 512 thr = 8 waves (2x4).
// Ring-4 LDS K-tile buffers, stage lead 3 tiles, counted vmcnt per K-tile,
// raw s_barrier, setprio around MFMA clusters. Swizzle g' = g ^ ((row>>1)&3)
// applied both-sides (pre-swizzled global source + swizzled ds_read).
// EPI: 0=plain bf16  1=fp32  2=silu bf16  4=wv (*rinv*gate)  5=rel-shift store
template<int MREP, int EPI>
__launch_bounds__(512, 2)
__global__ void gemm256_k(GemmP p) {
  constexpr int BM = MREP * 32;
  constexpr int CA = MREP / 4;          // A-stage loads per thread
  constexpr int LPT = CA + 2;           // loads per K-tile per thread
  const int bxi = p.kend_mode ? ((int)gridDim.x - 1 - (int)blockIdx.x) : (int)blockIdx.x;
  const int i0 = bxi * BM;
  const int j0 = blockIdx.y * 256;
  const int b  = blockIdx.z;
  if (p.causal && j0 > i0) return;
  const unsigned short* Ag = p.A + (long)b * p.sA + (long)i0 * p.lda;
  const unsigned short* Bg = p.B + (long)b * p.sB + (long)j0 * p.ldb;
  const int kend = p.kend_mode ? min(p.K, i0 + BM) : p.K;
  const int NT = kend >> 5;             // K-tiles of 32

  __shared__ unsigned short As[4][BM * 32];
  __shared__ unsigned short Bs[4][256 * 32];

  const int tid = threadIdx.x;
  const int w = tid >> 6, l = tid & 63;
  const int wr = w >> 2, wc = w & 3;
  const int lrow = l >> 2;
  const int swz = ((l & 3) ^ ((l >> 3) & 3)) * 8;   // source-side swizzled granule

  auto stageA = [&](int t) {
#pragma unroll
    for (int i = 0; i < CA; ++i) {
      const int c = w * CA + i;
      gload_lds16((const void*)(Ag + (long)(c * 16 + lrow) * p.lda + t * 32 + swz),
                  (void*)(&As[t & 3][c * 512]));
    }
  };
  auto stageB = [&](int t) {
#pragma unroll
    for (int i = 0; i < 2; ++i) {
      const int c = w * 2 + i;
      gload_lds16((const void*)(Bg + (long)(c * 16 + lrow) * p.ldb + t * 32 + swz),
                  (void*)(&Bs[t & 3][c * 512]));
    }
  };

  f32x4 acc[MREP][4];
#pragma unroll
  for (int m = 0; m < MREP; ++m)
#pragma unroll
    for (int n = 0; n < 4; ++n) acc[m][n] = (f32x4){0.f, 0.f, 0.f, 0.f};

  const int fr = l & 15, fq = l >> 4;
  const int rg = (fq ^ ((fr >> 1) & 3)) * 8;        // read-side swizzled granule
  const int aoff = (wr * (MREP * 16) + fr) * 32 + rg;
  const int boff = (wc * 64 + fr) * 32 + rg;

  // prologue: stage tiles 0,1,2
  stageA(0); stageB(0);
  if (NT > 1) { stageA(1); stageB(1); }
  if (NT > 2) { stageA(2); stageB(2); }

  for (int t = 0; t < NT; ++t) {
    const unsigned short* as = &As[t & 3][0];
    const unsigned short* bs = &Bs[t & 3][0];
    const int rem = NT - 1 - t;
    if (rem >= 2)      vmwait<2 * LPT>();   // tiles t+1,t+2 stay in flight
    else if (rem == 1) vmwait<LPT>();
    else               vmwait<0>();
    __builtin_amdgcn_s_barrier();
    __builtin_amdgcn_sched_barrier(0);

    // phase 0: B frags + first half of A frags; stage A(t+3)
    s16x8 bf[4];
#pragma unroll
    for (int n = 0; n < 4; ++n) bf[n] = *(const s16x8*)(bs + boff + n * 512);
    s16x8 af0[MREP / 2];
#pragma unroll
    for (int m = 0; m < MREP / 2; ++m) af0[m] = *(const s16x8*)(as + aoff + m * 512);
    if (t + 3 < NT) stageA(t + 3);
    __builtin_amdgcn_s_barrier();
    __builtin_amdgcn_s_setprio(1);
#pragma unroll
    for (int m = 0; m < MREP / 2; ++m)
#pragma unroll
      for (int n = 0; n < 4; ++n)
        acc[m][n] = __builtin_amdgcn_mfma_f32_16x16x32_bf16(af0[m], bf[n], acc[m][n], 0, 0, 0);
    __builtin_amdgcn_s_setprio(0);

    // phase 1: second half of A frags; stage B(t+3)
    s16x8 af1[MREP / 2];
#pragma unroll
    for (int m = 0; m < MREP / 2; ++m)
      af1[m] = *(const s16x8*)(as + aoff + (m + MREP / 2) * 512);
    if (t + 3 < NT) stageB(t + 3);
    __builtin_amdgcn_s_barrier();
    __builtin_amdgcn_s_setprio(1);
#pragma unroll
    for (int m = 0; m < MREP / 2; ++m)
#pragma unroll
      for (int n = 0; n < 4; ++n)
        acc[m + MREP / 2][n] =
            __builtin_amdgcn_mfma_f32_16x16x32_bf16(af1[m], bf[n], acc[m + MREP / 2][n], 0, 0, 0);
    __builtin_amdgcn_s_setprio(0);
  }

  // epilogue: C/D layout col = lane&15, row = (lane>>4)*4 + e
  const int rbase = i0 + wr * (MREP * 16) + fq * 4;
  const int cbase = j0 + wc * 64 + fr;
#pragma unroll
  for (int m = 0; m < MREP; ++m) {
#pragma unroll
    for (int n = 0; n < 4; ++n) {
      const int col = cbase + n * 16;
#pragma unroll
      for (int e = 0; e < 4; ++e) {
        const int row = rbase + m * 16 + e;
        const float val = acc[m][n][e];
        if constexpr (EPI == 0) {
          ((unsigned short*)p.C)[(long)b * p.sC + (long)row * p.ldc + col] = f2b(val);
        } else if constexpr (EPI == 1) {
          ((float*)p.C)[(long)b * p.sC + (long)row * p.ldc + col] = val;
        } else if constexpr (EPI == 2) {
          ((unsigned short*)p.C)[(long)b * p.sC + (long)row * p.ldc + col] =
              f2b(val / (1.f + __expf(-val)));
        } else if constexpr (EPI == 4) {
          const long coff = (long)b * p.sC + (long)row * p.ldc + col;
          const float g = b2f(p.gate[coff]);
          const float r = p.rinv[b * p.M + row];
          ((unsigned short*)p.C)[coff] = f2b(val * r * g);
        } else if constexpr (EPI == 5) {  // rel-shift: scores_bd[i, i-d] = val at (row=i, col=d)
          if (col <= row)
            ((unsigned short*)p.C)[(long)b * p.sC + (long)row * p.ldc + (row - col)] = f2b(val);
        }
      }
    }
  }
}

// ---------- 128x128 GEMM (m97 structure), kept for small-N GEMMs ----------
// EPI: 0=plain bf16  3=qu/qv/kk split
template<int EPI>
__launch_bounds__(256)
__global__ void gemm_bt_k(GemmP p) {
  const int i0 = blockIdx.x * 128;
  const int j0 = blockIdx.y * 128;
  const int b  = blockIdx.z;
  if (p.causal && j0 > i0) return;
  const unsigned short* A = p.A + (long)b * p.sA + (long)i0 * p.lda;
  const unsigned short* B = p.B + (long)b * p.sB + (long)j0 * p.ldb;
  const int kend = p.kend_mode ? min(p.K, i0 + 128) : p.K;

  __shared__ unsigned short As[128 * 32];
  __shared__ unsigned short Bs[128 * 32];

  const int tid = threadIdx.x;
  const int w = tid >> 6, l = tid & 63;
  const int wr = w >> 1, wc = w & 1;

  f32x4 acc[4][4];
#pragma unroll
  for (int m = 0; m < 4; ++m)
#pragma unroll
    for (int n = 0; n < 4; ++n) acc[m][n] = (f32x4){0.f, 0.f, 0.f, 0.f};

  const int srow = (l >> 2);
  const int scol = ((l & 3) ^ ((l >> 3) & 3)) * 8;   // swizzled source granule
  const unsigned short* ga0 = A + (long)(w * 16 + srow) * p.lda + scol;
  const unsigned short* ga1 = A + (long)((w + 4) * 16 + srow) * p.lda + scol;
  const unsigned short* gb0 = B + (long)(w * 16 + srow) * p.ldb + scol;
  const unsigned short* gb1 = B + (long)((w + 4) * 16 + srow) * p.ldb + scol;
  unsigned short* la0 = As + w * 512;
  unsigned short* la1 = As + (w + 4) * 512;
  unsigned short* lb0 = Bs + w * 512;
  unsigned short* lb1 = Bs + (w + 4) * 512;

  const int rg = ((l >> 4) ^ (((l & 15) >> 1) & 3)) * 8;  // swizzled read granule
  const unsigned short* ap = As + ((wr * 64) + (l & 15)) * 32 + rg;
  const unsigned short* bp = Bs + ((wc * 64) + (l & 15)) * 32 + rg;

  for (int k0 = 0; k0 < kend; k0 += 32) {
    gload_lds16(ga0 + k0, la0);
    gload_lds16(ga1 + k0, la1);
    gload_lds16(gb0 + k0, lb0);
    gload_lds16(gb1 + k0, lb1);
    __syncthreads();
    s16x8 af[4], bfr[4];
#pragma unroll
    for (int m = 0; m < 4; ++m) af[m] = *(const s16x8*)(ap + m * 16 * 32);
#pragma unroll
    for (int n = 0; n < 4; ++n) bfr[n] = *(const s16x8*)(bp + n * 16 * 32);
#pragma unroll
    for (int m = 0; m < 4; ++m)
#pragma unroll
      for (int n = 0; n < 4; ++n)
        acc[m][n] = __builtin_amdgcn_mfma_f32_16x16x32_bf16(af[m], bfr[n], acc[m][n], 0, 0, 0);
    __syncthreads();
  }

  const int rbase = i0 + wr * 64 + (l >> 4) * 4;
  const int cbase = j0 + wc * 64 + (l & 15);
#pragma unroll
  for (int m = 0; m < 4; ++m) {
#pragma unroll
    for (int n = 0; n < 4; ++n) {
      const int col = cbase + n * 16;
#pragma unroll
      for (int e = 0; e < 4; ++e) {
        const int row = rbase + m * 16 + e;
        const float val = acc[m][n][e];
        if constexpr (EPI == 0) {
          ((unsigned short*)p.C)[(long)b * p.sC + (long)row * p.ldc + col] = f2b(val);
        } else if constexpr (EPI == 3) {
          if (j0 == 0) {
            const float q = val * p.invtau;
            const long o = (long)row * 128 + col;
            ((unsigned short*)p.C)[o] = f2b(q + p.uvec[col]);
            p.qv_out[o] = f2b(q + p.vvec[col]);
          } else {
            p.kk_out[(long)row * 128 + (col - 128)] = f2b(val);
          }
        }
      }
    }
  }
}

// ---------- RMSNorm: x[row,1024] -> bf16 x_tilde ----------
__launch_bounds__(256)
__global__ void rmsnorm_k(const float* __restrict__ x, const float* __restrict__ g,
                          unsigned short* __restrict__ xt) {
  const long row = blockIdx.x;
  const float* xr = x + row * 1024;
  const int t = threadIdx.x;
  const float4 v = ((const float4*)xr)[t];
  float ss = v.x * v.x + v.y * v.y + v.z * v.z + v.w * v.w;
#pragma unroll
  for (int o = 1; o < 64; o <<= 1) ss += __shfl_xor(ss, o);
  __shared__ float wsum[4];
  if ((t & 63) == 0) wsum[t >> 6] = ss;
  __syncthreads();
  const float tot = wsum[0] + wsum[1] + wsum[2] + wsum[3];
  const float r = 1.0f / sqrtf(tot * (1.0f / 1024.0f) + 1e-6f);
  const float4 gv = ((const float4*)g)[t];
  u16x4 o;
  o.x = f2b(v.x * r * gv.x); o.y = f2b(v.y * r * gv.y);
  o.z = f2b(v.z * r * gv.z); o.w = f2b(v.w * r * gv.w);
  ((u16x4*)(xt + row * 1024))[t] = o;
}

// ---------- sinusoid table (UNFLIPPED: rr[d] = xl_r[T-1-d] = sin_noflip[d] @ W_r) ----------
__launch_bounds__(256)
__global__ void sinemb_k(unsigned short* __restrict__ emb) {
  const int idx = blockIdx.x * 256 + threadIdx.x;
  const int t = idx >> 10, w = idx & 1023;
  const int h = w & 511;
  const float inv = __expf(-(float)h * (9.2103403719761836f / 512.0f)); // LAM^(-2h/1024)
  const float pre = (float)t * inv;
  const float val = (w < 512) ? sinf(pre) : cosf(pre);
  emb[idx] = f2b(val);
}

// ---------- transpose-cast fp32 [R,C] -> bf16 [C,R] ----------
__launch_bounds__(256)
__global__ void transcast_k(const float* __restrict__ in, unsigned short* __restrict__ out,
                            int R, int C) {
  __shared__ float tile[32][33];
  const int c0 = blockIdx.x * 32, r0 = blockIdx.y * 32;
  const int tx = threadIdx.x & 31, ty = threadIdx.x >> 5;
#pragma unroll
  for (int k = 0; k < 4; ++k)
    tile[ty + k * 8][tx] = in[(long)(r0 + ty + k * 8) * C + c0 + tx];
  __syncthreads();
#pragma unroll
  for (int k = 0; k < 4; ++k)
    out[(long)(c0 + ty + k * 8) * R + r0 + tx] = f2b(tile[tx][ty + k * 8]);
}

// ---------- E-combine: E = exp(min(AC + BDs, 60)) masked, in-place over AC ----------
// BDs holds scores_bd already rel-shifted (BDs[i, j] valid for j <= i).
__launch_bounds__(256)
__global__ void ecombine_k(unsigned short* __restrict__ E_, const unsigned short* __restrict__ BDs_,
                           float* __restrict__ stats, int T) {
  const int i0 = blockIdx.x * 128, j0 = blockIdx.y * 128, b = blockIdx.z;
  if (j0 > i0) return;
  const long base = (long)b * T * T;
  unsigned short* E = E_ + base;
  const unsigned short* BD = BDs_ + base;
  const int tid = threadIdx.x;
#pragma unroll
  for (int pss = 0; pss < 2; ++pss) {
    const int slot = tid + 256 * pss;
    const int r = slot >> 2, ch = slot & 3;     // 4 threads per row, 32 cols each
    const int i = i0 + r;
    const long rowb = (long)i * T;
    const int jbase = j0 + ch * 32;
    float sum = 0.f;
    const u16x8* acp = (const u16x8*)(E + rowb + jbase);
    const u16x8* bdp = (const u16x8*)(BD + rowb + jbase);
    u16x8 outv[4];
    if (jbase + 31 <= i) {                      // fully inside causal region
#pragma unroll
      for (int q = 0; q < 4; ++q) {
        const u16x8 av = acp[q], bv = bdp[q];
#pragma unroll
        for (int c = 0; c < 8; ++c) {
          const float e = __expf(fminf(b2f(av[c]) + b2f(bv[c]), 60.f));
          sum += e;
          outv[q][c] = f2b(e);
        }
      }
    } else {
#pragma unroll
      for (int q = 0; q < 4; ++q) {
        const u16x8 av = acp[q], bv = bdp[q];
#pragma unroll
        for (int c = 0; c < 8; ++c) {
          const int j = jbase + q * 8 + c;
          float e = 0.f;
          if (j <= i) { e = __expf(fminf(b2f(av[c]) + b2f(bv[c]), 60.f)); sum += e; }
          outv[q][c] = f2b(e);
        }
      }
    }
    u16x8* eop = (u16x8*)(E + rowb + jbase);
#pragma unroll
    for (int q = 0; q < 4; ++q) eop[q] = outv[q];
    sum += __shfl_xor(sum, 1);
    sum += __shfl_xor(sum, 2);
    if (ch == 0) stats[((long)(b * T + i) << 5) + (j0 >> 7)] = sum;
  }
}

// ---------- per-row 1/sum ----------
__global__ void rowinv_k(const float* __restrict__ stats, float* __restrict__ rinv,
                         int T, int BT) {
  const int idx = blockIdx.x * 256 + threadIdx.x;
  if (idx >= BT) return;
  const int i = idx & (T - 1);
  const int nt = (i >> 7) + 1;
  const float* st = stats + ((long)idx << 5);
  float s = 0.f;
  for (int jt = 0; jt < nt; ++jt) s += st[jt];
  rinv[idx] = 1.0f / s;
}

// ---------- host ----------
extern "C" void kernel_launch(void* const* d_in, const int* in_sizes, int n_in,
                              void* d_out, int out_size, void* d_ws, size_t ws_size,
                              hipStream_t stream) {
  const float* x    = (const float*)d_in[0];
  const float* g_ln = (const float*)d_in[1];
  const float* W_q  = (const float*)d_in[2];
  const float* W_k  = (const float*)d_in[3];
  const float* W_v  = (const float*)d_in[4];
  const float* W_g  = (const float*)d_in[5];
  const float* W_r  = (const float*)d_in[6];
  const float* xl_u = (const float*)d_in[7];
  const float* xl_v = (const float*)d_in[8];
  const float* W_o  = (const float*)d_in[9];
  float* out = (float*)d_out;

  const int B = 2, T = 4096, D = 1024, K = 128, V = 2048;
  const int BT = B * T;

  char* ws = (char*)d_ws;
  size_t off = 0;
  auto alloc = [&](size_t bytes) -> void* {
    void* p = ws + off; off += (bytes + 255) & ~(size_t)255; return p;
  };
  unsigned short* XT   = (unsigned short*)alloc((size_t)BT * D * 2);
  unsigned short* WQKT = (unsigned short*)alloc((size_t)256 * D * 2);
  unsigned short* WVT  = (unsigned short*)alloc((size_t)V * D * 2);
  unsigned short* WGT  = (unsigned short*)alloc((size_t)V * D * 2);
  unsigned short* WRT  = (unsigned short*)alloc((size_t)K * D * 2);
  unsigned short* WOT  = (unsigned short*)alloc((size_t)D * V * 2);
  unsigned short* QU   = (unsigned short*)alloc((size_t)BT * K * 2);
  unsigned short* QV   = (unsigned short*)alloc((size_t)BT * K * 2);
  unsigned short* KKb  = (unsigned short*)alloc((size_t)BT * K * 2);
  unsigned short* RR   = (unsigned short*)alloc((size_t)T * K * 2);
  unsigned short* VVT  = (unsigned short*)alloc((size_t)V * BT * 2);
  unsigned short* GATE = (unsigned short*)alloc((size_t)BT * V * 2);
  float* STATS         = (float*)alloc((size_t)BT * 32 * 4);
  float* RINV          = (float*)alloc((size_t)BT * 4);
  unsigned short* AC   = (unsigned short*)alloc((size_t)B * T * T * 2);
  unsigned short* BD2  = (unsigned short*)alloc((size_t)B * T * T * 2);
  unsigned short* EMB  = BD2;  // [T,D] bf16, dead before BD2 is written
  unsigned short* WVG  = BD2;  // [BT,V] bf16, written after BD2 is consumed
  if (off > ws_size) return;   // loud failure (output stays zero)
  (void)in_sizes; (void)n_in; (void)out_size;

  const float invtau = 0.08838834764831845f;  // 1/sqrt(128)

  transcast_k<<<dim3(K / 32, D / 32), 256, 0, stream>>>(W_q, WQKT, D, K);
  transcast_k<<<dim3(K / 32, D / 32), 256, 0, stream>>>(W_k, WQKT + (size_t)K * D, D, K);
  transcast_k<<<dim3(V / 32, D / 32), 256, 0, stream>>>(W_v, WVT, D, V);
  transcast_k<<<dim3(V / 32, D / 32), 256, 0, stream>>>(W_g, WGT, D, V);
  transcast_k<<<dim3(K / 32, D / 32), 256, 0, stream>>>(W_r, WRT, D, K);
  transcast_k<<<dim3(D / 32, V / 32), 256, 0, stream>>>(W_o, WOT, V, D);
  rmsnorm_k<<<BT, 256, 0, stream>>>(x, g_ln, XT);
  sinemb_k<<<(T * D) / 256, 256, 0, stream>>>(EMB);

  { // qu/qv/k fused: A=XT[8192,1024], B=WQKT[256,1024]
    GemmP p{}; p.A = XT; p.B = WQKT; p.C = QU;
    p.M = BT; p.N = 256; p.K = D; p.lda = D; p.ldb = D; p.ldc = K;
    p.uvec = xl_u; p.vvec = xl_v; p.qv_out = QV; p.kk_out = KKb; p.invtau = invtau;
    gemm_bt_k<3><<<dim3(BT / 128, 2, 1), 256, 0, stream>>>(p);
  }
  { // rr = sin_noflip @ W_r : A=EMB[4096,1024], B=WRT[128,1024]
    GemmP p{}; p.A = EMB; p.B = WRT; p.C = RR;
    p.M = T; p.N = K; p.K = D; p.lda = D; p.ldb = D; p.ldc = K;
    gemm_bt_k<0><<<dim3(T / 128, K / 128, 1), 256, 0, stream>>>(p);
  }
  { // v^T: A=WVT[2048,1024], B=XT[8192,1024] -> VVT[2048,8192]
    GemmP p{}; p.A = WVT; p.B = XT; p.C = VVT;
    p.M = V; p.N = BT; p.K = D; p.lda = D; p.ldb = D; p.ldc = BT;
    gemm256_k<8, 0><<<dim3(V / 256, BT / 256, 1), 512, 0, stream>>>(p);
  }
  { // gate = silu(x~ @ W_g): A=XT, B=WGT -> GATE[8192,2048]
    GemmP p{}; p.A = XT; p.B = WGT; p.C = GATE;
    p.M = BT; p.N = V; p.K = D; p.lda = D; p.ldb = D; p.ldc = V;
    gemm256_k<8, 2><<<dim3(BT / 256, V / 256, 1), 512, 0, stream>>>(p);
  }
  { // AC = qu . k^T (causal tiles), batched
    GemmP p{}; p.A = QU; p.B = KKb; p.C = AC;
    p.sA = (long)T * K; p.sB = (long)T * K; p.sC = (long)T * T;
    p.M = T; p.N = T; p.K = K; p.lda = K; p.ldb = K; p.ldc = T; p.causal = 1;
    gemm256_k<8, 0><<<dim3(T / 256, T / 256, B), 512, 0, stream>>>(p);
  }
  { // BD rel-shifted: scores_bd[b,i,i-d] = (qv . rr^T)[b,i,d], causal in (i,d)
    GemmP p{}; p.A = QV; p.B = RR; p.C = BD2;
    p.sA = (long)T * K; p.sB = 0; p.sC = (long)T * T;
    p.M = T; p.N = T; p.K = K; p.lda = K; p.ldb = K; p.ldc = T; p.causal = 1;
    gemm256_k<8, 5><<<dim3(T / 256, T / 256, B), 512, 0, stream>>>(p);
  }
  ecombine_k<<<dim3(T / 128, T / 128, B), 256, 0, stream>>>(AC, BD2, STATS, T);
  rowinv_k<<<BT / 256, 256, 0, stream>>>(STATS, RINV, T, BT);
  { // wv = (E @ v) * rinv * gate : A=E(AC), B=VVT(+b*T cols), k bounded per row-tile
    GemmP p{}; p.A = AC; p.B = VVT; p.C = WVG;
    p.sA = (long)T * T; p.sB = T; p.sC = (long)T * V;
    p.M = T; p.N = V; p.K = T; p.lda = T; p.ldb = BT; p.ldc = V;
    p.kend_mode = 1; p.rinv = RINV; p.gate = GATE;
    gemm256_k<4, 4><<<dim3(T / 128, V / 256, B), 512, 0, stream>>>(p);
  }
  { // res = wvg @ W_o : A=WVG[8192,2048], B=WOT[1024,2048] -> fp32 out
    GemmP p{}; p.A = WVG; p.B = WOT; p.C = out;
    p.M = BT; p.N = D; p.K = V; p.lda = V; p.ldb = V; p.ldc = D;
    gemm256_k<4, 1><<<dim3(BT / 128, D / 256, 1), 512, 0, stream>>>(p);
  }
}

// Round 3
// 408.826 us; speedup vs baseline: 1.5204x; 1.2879x over previous
//
#include <hip/hip_runtime.h>
#include <hip/hip_bf16.h>
#include <stdint.h>

// ---------- types & helpers ----------
typedef __attribute__((ext_vector_type(4))) float f32x4;
typedef __attribute__((ext_vector_type(8))) short s16x8;      // MFMA bf16 frag (8 bf16)
typedef __attribute__((ext_vector_type(8))) unsigned short u16x8;
typedef __attribute__((ext_vector_type(4))) unsigned short u16x4;

static __device__ __forceinline__ float b2f(unsigned short u) {
  union { unsigned int i; float f; } v; v.i = ((unsigned int)u) << 16; return v.f;
}
static __device__ __forceinline__ unsigned short f2b(float f) {
  unsigned int x = __float_as_uint(f);
  return (unsigned short)((x + 0x7fffu + ((x >> 16) & 1u)) >> 16);  // RNE
}

typedef __attribute__((address_space(1))) const void gconst_t;
typedef __attribute__((address_space(3))) void lds_t;
static __device__ __forceinline__ void gload_lds16(const void* g, void* l) {
  __builtin_amdgcn_global_load_lds((gconst_t*)g, (lds_t*)l, 16, 0, 0);
}

template<int N>
static __device__ __forceinline__ void vmwait() {
  asm volatile("s_waitcnt vmcnt(%0)" :: "n"(N) : "memory");
}

struct GemmP {
  const unsigned short* A; const unsigned short* B; void* C;
  long sA, sB, sC;                 // batch strides (elements)
  int M, N, K, lda, ldb, ldc;
  int causal, kend_mode;
  int gxs, gys, qchunk;            // log2(gridX), log2(gridY), nwg/8
  const float* uvec; const float* vvec;
  unsigned short* qv_out; unsigned short* kk_out; float invtau;
  const float* rinv; const unsigned short* gate;
  const unsigned short* bds; float* stats;
};

// ---------- 2-phase ring-3 GEMM: C[m,n] = sum_k A[m,k]*B[n,k] ----------
// BM=128, BN=NREP*64, BK=32. 512 thr = 8 waves (2 row x 4 col), wave tile 64x(NREP*16).
// LDS ring-3 (72KB @NREP=4 -> 2 blocks/CU). One barrier + one counted vmcnt per K-tile
// (drain 0 only on last iter), 4*NREP-MFMA cluster under setprio. Both-sides granule
// swizzle g^=((row>>1)&3). Bijective XCD q-chunk remap for L2 panel locality.
// EPI: 0=bf16  1=fp32  2=silu bf16  4=wv(*rinv*gate)  5=rel-shift scatter  6=exp-fuse
template<int NREP, int EPI>
__launch_bounds__(512, 4)
__global__ void gemm2p_k(GemmP p) {
  constexpr int BN = NREP * 64;
  constexpr int CB = NREP / 2;          // B-stage loads per thread per K-tile
  constexpr int LPT = 1 + CB;
  // XCD-aware bijective remap (nwg % 8 == 0 for all launches)
  const int lin = (int)blockIdx.x + (((int)blockIdx.y + (int)blockIdx.z * (int)gridDim.y) << p.gxs);
  const int wg = (lin & 7) * p.qchunk + (lin >> 3);
  int ii = wg & ((1 << p.gxs) - 1);
  const int jj = (wg >> p.gxs) & ((1 << p.gys) - 1);
  const int b  = wg >> (p.gxs + p.gys);
  if (p.kend_mode) ii = (1 << p.gxs) - 1 - ii;   // big-K blocks first
  const int i0 = ii * 128, j0 = jj * BN;
  if (p.causal && j0 > i0 + 127) return;
  const unsigned short* Ag = p.A + (long)b * p.sA + (long)i0 * p.lda;
  const unsigned short* Bg = p.B + (long)b * p.sB + (long)j0 * p.ldb;
  const int kend = p.kend_mode ? min(p.K, i0 + 128) : p.K;
  const int NT = kend >> 5;

  __shared__ unsigned short As[3][128 * 32];
  __shared__ unsigned short Bs[3][BN * 32];

  const int tid = threadIdx.x;
  const int w = tid >> 6, l = tid & 63;
  const int wr = w >> 2, wc = w & 3;
  const int lrow = l >> 2;
  const int swz = ((l & 3) ^ ((l >> 3) & 3)) * 8;   // source-side swizzled granule

  auto stage = [&](int t, int bi) {
    gload_lds16((const void*)(Ag + (long)(w * 16 + lrow) * p.lda + t * 32 + swz),
                (void*)(&As[bi][w * 512]));
#pragma unroll
    for (int i = 0; i < CB; ++i) {
      const int c = w * CB + i;
      gload_lds16((const void*)(Bg + (long)(c * 16 + lrow) * p.ldb + t * 32 + swz),
                  (void*)(&Bs[bi][c * 512]));
    }
  };

  f32x4 acc[4][NREP];
#pragma unroll
  for (int m = 0; m < 4; ++m)
#pragma unroll
    for (int n = 0; n < NREP; ++n) acc[m][n] = (f32x4){0.f, 0.f, 0.f, 0.f};

  const int fr = l & 15, fq = l >> 4;
  const int rg = (fq ^ ((fr >> 1) & 3)) * 8;        // read-side swizzled granule
  const int aoff = (wr * 64 + fr) * 32 + rg;
  const int boff = (wc * (NREP * 16) + fr) * 32 + rg;

  stage(0, 0);
  if (NT > 1) stage(1, 1);

  int bi = 0;
  for (int t = 0; t < NT; ++t) {
    if (t == NT - 1) vmwait<0>(); else vmwait<LPT>();
    __builtin_amdgcn_s_barrier();
    __builtin_amdgcn_sched_barrier(0);
    const unsigned short* as = &As[bi][0];
    const unsigned short* bs = &Bs[bi][0];
    s16x8 af[4], bf[NREP];
#pragma unroll
    for (int m = 0; m < 4; ++m) af[m] = *(const s16x8*)(as + aoff + m * 512);
#pragma unroll
    for (int n = 0; n < NREP; ++n) bf[n] = *(const s16x8*)(bs + boff + n * 512);
    if (t + 2 < NT) {
      int bi2 = bi + 2; if (bi2 >= 3) bi2 -= 3;
      stage(t + 2, bi2);
    }
    __builtin_amdgcn_s_setprio(1);
#pragma unroll
    for (int m = 0; m < 4; ++m)
#pragma unroll
      for (int n = 0; n < NREP; ++n)
        acc[m][n] = __builtin_amdgcn_mfma_f32_16x16x32_bf16(af[m], bf[n], acc[m][n], 0, 0, 0);
    __builtin_amdgcn_s_setprio(0);
    bi = (bi + 1 == 3) ? 0 : bi + 1;
  }

  // epilogue: C/D layout col = lane&15, row = (lane>>4)*4 + e
  const int rbase = i0 + wr * 64 + fq * 4;
  const int cbase = j0 + wc * (NREP * 16) + fr;
  const long tb = (long)b * p.sC;

  if constexpr (EPI == 6) {
    float ps[16];
#pragma unroll
    for (int t = 0; t < 16; ++t) ps[t] = 0.f;
#pragma unroll
    for (int m = 0; m < 4; ++m) {
#pragma unroll
      for (int n = 0; n < NREP; ++n) {
        const int col = cbase + n * 16;
#pragma unroll
        for (int e = 0; e < 4; ++e) {
          const int row = rbase + m * 16 + e;
          const long o = tb + (long)row * p.ldc + col;
          float ev = 0.f;
          if (col <= row) {
            const float s = acc[m][n][e] + b2f(p.bds[o]);
            ev = __expf(fminf(s, 60.f));
          }
          ((unsigned short*)p.C)[o] = f2b(ev);
          ps[m * 4 + e] += ev;
        }
      }
    }
#pragma unroll
    for (int t = 0; t < 16; ++t) {
      float v = ps[t];
      v += __shfl_xor(v, 1); v += __shfl_xor(v, 2);
      v += __shfl_xor(v, 4); v += __shfl_xor(v, 8);
      ps[t] = v;
    }
    if (fr == 0) {
#pragma unroll
      for (int t = 0; t < 16; ++t) {
        const int row = rbase + (t >> 2) * 16 + (t & 3);
        p.stats[((long)(b * p.M + row) * 16 + jj) * 4 + wc] = ps[t];
      }
    }
    return;
  }

#pragma unroll
  for (int m = 0; m < 4; ++m) {
#pragma unroll
    for (int n = 0; n < NREP; ++n) {
      const int col = cbase + n * 16;
#pragma unroll
      for (int e = 0; e < 4; ++e) {
        const int row = rbase + m * 16 + e;
        const float val = acc[m][n][e];
        if constexpr (EPI == 0) {
          ((unsigned short*)p.C)[tb + (long)row * p.ldc + col] = f2b(val);
        } else if constexpr (EPI == 1) {
          ((float*)p.C)[tb + (long)row * p.ldc + col] = val;
        } else if constexpr (EPI == 2) {
          ((unsigned short*)p.C)[tb + (long)row * p.ldc + col] =
              f2b(val / (1.f + __expf(-val)));
        } else if constexpr (EPI == 4) {
          const long coff = tb + (long)row * p.ldc + col;
          const float g = b2f(p.gate[coff]);
          const float r = p.rinv[b * p.M + row];
          ((unsigned short*)p.C)[coff] = f2b(val * r * g);
        } else if constexpr (EPI == 5) {  // rel-shift: scores_bd[i, i-col] = val
          if (col <= row)
            ((unsigned short*)p.C)[tb + (long)row * p.ldc + (row - col)] = f2b(val);
        }
      }
    }
  }
}

// ---------- 128x128 GEMM (m97 structure) for small-N GEMMs ----------
// EPI: 0=plain bf16  3=qu/qv/kk split
template<int EPI>
__launch_bounds__(256)
__global__ void gemm_bt_k(GemmP p) {
  const int i0 = blockIdx.x * 128;
  const int j0 = blockIdx.y * 128;
  const int b  = blockIdx.z;
  const unsigned short* A = p.A + (long)b * p.sA + (long)i0 * p.lda;
  const unsigned short* B = p.B + (long)b * p.sB + (long)j0 * p.ldb;
  const int kend = p.K;

  __shared__ unsigned short As[128 * 32];
  __shared__ unsigned short Bs[128 * 32];

  const int tid = threadIdx.x;
  const int w = tid >> 6, l = tid & 63;
  const int wr = w >> 1, wc = w & 1;

  f32x4 acc[4][4];
#pragma unroll
  for (int m = 0; m < 4; ++m)
#pragma unroll
    for (int n = 0; n < 4; ++n) acc[m][n] = (f32x4){0.f, 0.f, 0.f, 0.f};

  const int srow = (l >> 2);
  const int scol = ((l & 3) ^ ((l >> 3) & 3)) * 8;
  const unsigned short* ga0 = A + (long)(w * 16 + srow) * p.lda + scol;
  const unsigned short* ga1 = A + (long)((w + 4) * 16 + srow) * p.lda + scol;
  const unsigned short* gb0 = B + (long)(w * 16 + srow) * p.ldb + scol;
  const unsigned short* gb1 = B + (long)((w + 4) * 16 + srow) * p.ldb + scol;
  unsigned short* la0 = As + w * 512;
  unsigned short* la1 = As + (w + 4) * 512;
  unsigned short* lb0 = Bs + w * 512;
  unsigned short* lb1 = Bs + (w + 4) * 512;

  const int rg = ((l >> 4) ^ (((l & 15) >> 1) & 3)) * 8;
  const unsigned short* ap = As + ((wr * 64) + (l & 15)) * 32 + rg;
  const unsigned short* bp = Bs + ((wc * 64) + (l & 15)) * 32 + rg;

  for (int k0 = 0; k0 < kend; k0 += 32) {
    gload_lds16(ga0 + k0, la0);
    gload_lds16(ga1 + k0, la1);
    gload_lds16(gb0 + k0, lb0);
    gload_lds16(gb1 + k0, lb1);
    __syncthreads();
    s16x8 af[4], bfr[4];
#pragma unroll
    for (int m = 0; m < 4; ++m) af[m] = *(const s16x8*)(ap + m * 16 * 32);
#pragma unroll
    for (int n = 0; n < 4; ++n) bfr[n] = *(const s16x8*)(bp + n * 16 * 32);
#pragma unroll
    for (int m = 0; m < 4; ++m)
#pragma unroll
      for (int n = 0; n < 4; ++n)
        acc[m][n] = __builtin_amdgcn_mfma_f32_16x16x32_bf16(af[m], bfr[n], acc[m][n], 0, 0, 0);
    __syncthreads();
  }

  const int rbase = i0 + wr * 64 + (l >> 4) * 4;
  const int cbase = j0 + wc * 64 + (l & 15);
#pragma unroll
  for (int m = 0; m < 4; ++m) {
#pragma unroll
    for (int n = 0; n < 4; ++n) {
      const int col = cbase + n * 16;
#pragma unroll
      for (int e = 0; e < 4; ++e) {
        const int row = rbase + m * 16 + e;
        const float val = acc[m][n][e];
        if constexpr (EPI == 0) {
          ((unsigned short*)p.C)[(long)b * p.sC + (long)row * p.ldc + col] = f2b(val);
        } else if constexpr (EPI == 3) {
          if (j0 == 0) {
            const float q = val * p.invtau;
            const long o = (long)row * 128 + col;
            ((unsigned short*)p.C)[o] = f2b(q + p.uvec[col]);
            p.qv_out[o] = f2b(q + p.vvec[col]);
          } else {
            p.kk_out[(long)row * 128 + (col - 128)] = f2b(val);
          }
        }
      }
    }
  }
}

// ---------- RMSNorm ----------
__launch_bounds__(256)
__global__ void rmsnorm_k(const float* __restrict__ x, const float* __restrict__ g,
                          unsigned short* __restrict__ xt) {
  const long row = blockIdx.x;
  const float* xr = x + row * 1024;
  const int t = threadIdx.x;
  const float4 v = ((const float4*)xr)[t];
  float ss = v.x * v.x + v.y * v.y + v.z * v.z + v.w * v.w;
#pragma unroll
  for (int o = 1; o < 64; o <<= 1) ss += __shfl_xor(ss, o);
  __shared__ float wsum[4];
  if ((t & 63) == 0) wsum[t >> 6] = ss;
  __syncthreads();
  const float tot = wsum[0] + wsum[1] + wsum[2] + wsum[3];
  const float r = 1.0f / sqrtf(tot * (1.0f / 1024.0f) + 1e-6f);
  const float4 gv = ((const float4*)g)[t];
  u16x4 o;
  o.x = f2b(v.x * r * gv.x); o.y = f2b(v.y * r * gv.y);
  o.z = f2b(v.z * r * gv.z); o.w = f2b(v.w * r * gv.w);
  ((u16x4*)(xt + row * 1024))[t] = o;
}

// ---------- sinusoid table (UNFLIPPED) ----------
__launch_bounds__(256)
__global__ void sinemb_k(unsigned short* __restrict__ emb) {
  const int idx = blockIdx.x * 256 + threadIdx.x;
  const int t = idx >> 10, w = idx & 1023;
  const int h = w & 511;
  const float inv = __expf(-(float)h * (9.2103403719761836f / 512.0f));
  const float pre = (float)t * inv;
  const float val = (w < 512) ? sinf(pre) : cosf(pre);
  emb[idx] = f2b(val);
}

// ---------- transpose-cast fp32 [R,C] -> bf16 [C,R] ----------
__launch_bounds__(256)
__global__ void transcast_k(const float* __restrict__ in, unsigned short* __restrict__ out,
                            int R, int C) {
  __shared__ float tile[32][33];
  const int c0 = blockIdx.x * 32, r0 = blockIdx.y * 32;
  const int tx = threadIdx.x & 31, ty = threadIdx.x >> 5;
#pragma unroll
  for (int k = 0; k < 4; ++k)
    tile[ty + k * 8][tx] = in[(long)(r0 + ty + k * 8) * C + c0 + tx];
  __syncthreads();
#pragma unroll
  for (int k = 0; k < 4; ++k)
    out[(long)(c0 + ty + k * 8) * R + r0 + tx] = f2b(tile[tx][ty + k * 8]);
}

// ---------- per-row 1/sum over stats[BT][16 jt][4 wc] ----------
__global__ void rowinv_k(const float* __restrict__ stats, float* __restrict__ rinv,
                         int T, int BT) {
  const int idx = blockIdx.x * 256 + threadIdx.x;
  if (idx >= BT) return;
  const int i = idx & (T - 1);
  const int nt = (i >> 8) + 1;
  const float* st = stats + (long)idx * 64;
  float s = 0.f;
  for (int jt = 0; jt < nt; ++jt)
    s += st[jt * 4] + st[jt * 4 + 1] + st[jt * 4 + 2] + st[jt * 4 + 3];
  rinv[idx] = 1.0f / s;
}

// ---------- host ----------
extern "C" void kernel_launch(void* const* d_in, const int* in_sizes, int n_in,
                              void* d_out, int out_size, void* d_ws, size_t ws_size,
                              hipStream_t stream) {
  const float* x    = (const float*)d_in[0];
  const float* g_ln = (const float*)d_in[1];
  const float* W_q  = (const float*)d_in[2];
  const float* W_k  = (const float*)d_in[3];
  const float* W_v  = (const float*)d_in[4];
  const float* W_g  = (const float*)d_in[5];
  const float* W_r  = (const float*)d_in[6];
  const float* xl_u = (const float*)d_in[7];
  const float* xl_v = (const float*)d_in[8];
  const float* W_o  = (const float*)d_in[9];
  float* out = (float*)d_out;

  const int B = 2, T = 4096, D = 1024, K = 128, V = 2048;
  const int BT = B * T;

  char* ws = (char*)d_ws;
  size_t off = 0;
  auto alloc = [&](size_t bytes) -> void* {
    void* p = ws + off; off += (bytes + 255) & ~(size_t)255; return p;
  };
  unsigned short* XT   = (unsigned short*)alloc((size_t)BT * D * 2);
  unsigned short* WQKT = (unsigned short*)alloc((size_t)256 * D * 2);
  unsigned short* WVT  = (unsigned short*)alloc((size_t)V * D * 2);
  unsigned short* WGT  = (unsigned short*)alloc((size_t)V * D * 2);
  unsigned short* WRT  = (unsigned short*)alloc((size_t)K * D * 2);
  unsigned short* WOT  = (unsigned short*)alloc((size_t)D * V * 2);
  unsigned short* QU   = (unsigned short*)alloc((size_t)BT * K * 2);
  unsigned short* QV   = (unsigned short*)alloc((size_t)BT * K * 2);
  unsigned short* KKb  = (unsigned short*)alloc((size_t)BT * K * 2);
  unsigned short* RR   = (unsigned short*)alloc((size_t)T * K * 2);
  unsigned short* VVT  = (unsigned short*)alloc((size_t)V * BT * 2);
  unsigned short* GATE = (unsigned short*)alloc((size_t)BT * V * 2);
  float* STATS         = (float*)alloc((size_t)BT * 64 * 4);
  float* RINV          = (float*)alloc((size_t)BT * 4);
  unsigned short* EBUF = (unsigned short*)alloc((size_t)B * T * T * 2);  // E (exp scores)
  unsigned short* BD2  = (unsigned short*)alloc((size_t)B * T * T * 2);  // rel-shifted BD
  unsigned short* EMB  = BD2;  // [T,D] bf16, dead before BD2 is written
  unsigned short* WVG  = BD2;  // [BT,V] bf16, written after BD2 is consumed
  if (off > ws_size) return;
  (void)in_sizes; (void)n_in; (void)out_size;

  const float invtau = 0.08838834764831845f;  // 1/sqrt(128)

  transcast_k<<<dim3(K / 32, D / 32), 256, 0, stream>>>(W_q, WQKT, D, K);
  transcast_k<<<dim3(K / 32, D / 32), 256, 0, stream>>>(W_k, WQKT + (size_t)K * D, D, K);
  transcast_k<<<dim3(V / 32, D / 32), 256, 0, stream>>>(W_v, WVT, D, V);
  transcast_k<<<dim3(V / 32, D / 32), 256, 0, stream>>>(W_g, WGT, D, V);
  transcast_k<<<dim3(K / 32, D / 32), 256, 0, stream>>>(W_r, WRT, D, K);
  transcast_k<<<dim3(D / 32, V / 32), 256, 0, stream>>>(W_o, WOT, V, D);
  rmsnorm_k<<<BT, 256, 0, stream>>>(x, g_ln, XT);
  sinemb_k<<<(T * D) / 256, 256, 0, stream>>>(EMB);

  { // qu/qv/k fused
    GemmP p{}; p.A = XT; p.B = WQKT; p.C = QU;
    p.M = BT; p.N = 256; p.K = D; p.lda = D; p.ldb = D; p.ldc = K;
    p.uvec = xl_u; p.vvec = xl_v; p.qv_out = QV; p.kk_out = KKb; p.invtau = invtau;
    gemm_bt_k<3><<<dim3(BT / 128, 2, 1), 256, 0, stream>>>(p);
  }
  { // rr = sin_noflip @ W_r
    GemmP p{}; p.A = EMB; p.B = WRT; p.C = RR;
    p.M = T; p.N = K; p.K = D; p.lda = D; p.ldb = D; p.ldc = K;
    gemm_bt_k<0><<<dim3(T / 128, 1, 1), 256, 0, stream>>>(p);
  }
  { // v^T: A=WVT[2048,1024], B=XT[8192,1024] -> VVT[2048,8192]
    GemmP p{}; p.A = WVT; p.B = XT; p.C = VVT;
    p.M = V; p.N = BT; p.K = D; p.lda = D; p.ldb = D; p.ldc = BT;
    p.gxs = 4; p.gys = 5; p.qchunk = 64;
    gemm2p_k<4, 0><<<dim3(16, 32, 1), 512, 0, stream>>>(p);
  }
  { // gate = silu(x~ @ W_g)
    GemmP p{}; p.A = XT; p.B = WGT; p.C = GATE;
    p.M = BT; p.N = V; p.K = D; p.lda = D; p.ldb = D; p.ldc = V;
    p.gxs = 6; p.gys = 3; p.qchunk = 64;
    gemm2p_k<4, 2><<<dim3(64, 8, 1), 512, 0, stream>>>(p);
  }
  { // BD rel-shifted: scores_bd[b,i,i-d] = (qv . rr^T)[b,i,d]
    GemmP p{}; p.A = QV; p.B = RR; p.C = BD2;
    p.sA = (long)T * K; p.sB = 0; p.sC = (long)T * T;
    p.M = T; p.N = T; p.K = K; p.lda = K; p.ldb = K; p.ldc = T; p.causal = 1;
    p.gxs = 5; p.gys = 4; p.qchunk = 128;
    gemm2p_k<4, 5><<<dim3(32, 16, B), 512, 0, stream>>>(p);
  }
  { // E = exp(min(qu.k^T + BDs, 60)) causal-masked; per-(row,tile,wave) sums
    GemmP p{}; p.A = QU; p.B = KKb; p.C = EBUF;
    p.sA = (long)T * K; p.sB = (long)T * K; p.sC = (long)T * T;
    p.M = T; p.N = T; p.K = K; p.lda = K; p.ldb = K; p.ldc = T; p.causal = 1;
    p.bds = BD2; p.stats = STATS;
    p.gxs = 5; p.gys = 4; p.qchunk = 128;
    gemm2p_k<4, 6><<<dim3(32, 16, B), 512, 0, stream>>>(p);
  }
  rowinv_k<<<BT / 256, 256, 0, stream>>>(STATS, RINV, T, BT);
  { // wv = (E @ v) * rinv * gate
    GemmP p{}; p.A = EBUF; p.B = VVT; p.C = WVG;
    p.sA = (long)T * T; p.sB = T; p.sC = (long)T * V;
    p.M = T; p.N = V; p.K = T; p.lda = T; p.ldb = BT; p.ldc = V;
    p.kend_mode = 1; p.rinv = RINV; p.gate = GATE;
    p.gxs = 5; p.gys = 3; p.qchunk = 64;
    gemm2p_k<4, 4><<<dim3(32, 8, B), 512, 0, stream>>>(p);
  }
  { // res = wvg @ W_o -> fp32 out
    GemmP p{}; p.A = WVG; p.B = WOT; p.C = out;
    p.M = BT; p.N = D; p.K = V; p.lda = V; p.ldb = V; p.ldc = D;
    p.gxs = 6; p.gys = 3; p.qchunk = 64;
    gemm2p_k<2, 1><<<dim3(64, 8, 1), 512, 0, stream>>>(p);
  }
}